// Round 1
// baseline (514.783 us; speedup 1.0000x reference)
//
#include <hip/hip_runtime.h>
#include <stdint.h>
#include <stddef.h>

// ---------------------------------------------------------------------------
// TinySelfAttention on MI355X (gfx950), bf16 MFMA pipeline:
//   1) cast x -> bf16
//   2) transpose+cast W_qkv, W_out -> bf16 B^T form
//   3) GEMM (m97 structure): qkv = x @ W_qkv + b_qkv   (bf16 out)
//   4) transpose V slice of qkv -> per-head V^T (bf16)
//   5) flash attention (causal, online softmax), O in (b,s,h*hd) bf16
//   6) GEMM: y = O @ W_out + b_out  (fp32 out)
// ---------------------------------------------------------------------------

typedef __attribute__((ext_vector_type(8))) short bf16x8;   // 8 x bf16 = 4 VGPRs
typedef __attribute__((ext_vector_type(4))) float f32x4;    // MFMA accumulator

#define SOFT_SCALE 0.12751743075419806f  // (1/sqrt(128)) * log2(e)

__device__ __forceinline__ short f2bf(float f) {
  union { float f; unsigned u; } v; v.f = f;
  unsigned u = v.u + 0x7fffu + ((v.u >> 16) & 1u);  // RNE
  return (short)(u >> 16);
}

__device__ __forceinline__ void gload_lds16(const void* g, const void* l) {
  // async global->LDS, 16B per lane; LDS dest = wave-uniform base + lane*16
  __builtin_amdgcn_global_load_lds(
      (__attribute__((address_space(1))) void*)(uintptr_t)g,
      (__attribute__((address_space(3))) void*)(uintptr_t)l,
      16, 0, 0);
}

// ---------------------------------------------------------------------------
// Kernel 1: fp32 -> bf16 cast, 8 elems/thread
// ---------------------------------------------------------------------------
__global__ __launch_bounds__(256) void cast_f32_bf16(
    const float* __restrict__ in, short* __restrict__ out, int n8) {
  int i = blockIdx.x * 256 + threadIdx.x;
  if (i >= n8) return;
  float4 a = ((const float4*)in)[i * 2];
  float4 b = ((const float4*)in)[i * 2 + 1];
  bf16x8 o;
  o[0] = f2bf(a.x); o[1] = f2bf(a.y); o[2] = f2bf(a.z); o[3] = f2bf(a.w);
  o[4] = f2bf(b.x); o[5] = f2bf(b.y); o[6] = f2bf(b.z); o[7] = f2bf(b.w);
  ((bf16x8*)out)[i] = o;
}

// ---------------------------------------------------------------------------
// Kernel 2: W [K][N] fp32 -> WT [N][K] bf16, 32x32 tiles
// ---------------------------------------------------------------------------
__global__ __launch_bounds__(256) void transpose_cast_w(
    const float* __restrict__ W, short* __restrict__ WT, int K, int N) {
  __shared__ short t[32][33];
  int k0 = blockIdx.x * 32, n0 = blockIdx.y * 32;
  int r = threadIdx.x >> 3;
  int c = (threadIdx.x & 7) * 4;
  float4 v = *(const float4*)(W + (size_t)(k0 + r) * N + n0 + c);
  t[r][c + 0] = f2bf(v.x); t[r][c + 1] = f2bf(v.y);
  t[r][c + 2] = f2bf(v.z); t[r][c + 3] = f2bf(v.w);
  __syncthreads();
  short4 o;
  o.x = t[c + 0][r]; o.y = t[c + 1][r]; o.z = t[c + 2][r]; o.w = t[c + 3][r];
  *(short4*)(WT + (size_t)(n0 + r) * K + k0 + c) = o;
}

// ---------------------------------------------------------------------------
// Kernel 3: V slice of qkv (b,s, 4096 + h*128 + d) -> vT[bh][d][s], 64x64 tiles
// grid: (s-tiles=32, d-tiles=2, bh=32)
// ---------------------------------------------------------------------------
__global__ __launch_bounds__(256) void transpose_v(
    const short* __restrict__ qkv, short* __restrict__ vT) {
  __shared__ short t[64][72];
  int bh = blockIdx.z, b = bh >> 4, h = bh & 15;
  int s0 = blockIdx.x * 64, d0 = blockIdx.y * 64;
  const short* src = qkv + (size_t)b * 2048 * 6144 + 4096 + h * 128 + d0;
  short* dst = vT + (size_t)bh * 128 * 2048;
#pragma unroll
  for (int it = 0; it < 2; ++it) {
    int e = threadIdx.x * 8 + it * 2048;
    int sr = e >> 6, sc = e & 63;
    bf16x8 v = *(const bf16x8*)(src + (size_t)(s0 + sr) * 6144 + sc);
#pragma unroll
    for (int j = 0; j < 8; ++j) t[sr][sc + j] = v[j];
  }
  __syncthreads();
#pragma unroll
  for (int it = 0; it < 2; ++it) {
    int e = threadIdx.x * 8 + it * 2048;
    int dr = e >> 6, dc = e & 63;
    bf16x8 o;
#pragma unroll
    for (int j = 0; j < 8; ++j) o[j] = t[dc + j][dr];
    *(bf16x8*)(dst + (size_t)(d0 + dr) * 2048 + s0 + dc) = o;
  }
}

// ---------------------------------------------------------------------------
// Kernel 4: GEMM  C[M][N] = A[M][K] @ BT[N][K]^T + bias  (m97 structure)
// 128x128 tile, BK=32, 4 waves, 4x4 16x16x32 MFMAs per wave.
// BF16OUT=1 -> C is bf16 (short*), else fp32 (float*)
// ---------------------------------------------------------------------------
template <int BF16OUT>
__global__ __launch_bounds__(256) void gemm_bt(
    const short* __restrict__ A, const short* __restrict__ BT,
    void* __restrict__ Cv, const float* __restrict__ bias,
    int M, int N, int K) {
  __shared__ __align__(16) short As[128 * 32];
  __shared__ __align__(16) short Bs[128 * 32];
  const int tid = threadIdx.x;
  const int wave = tid >> 6, lane = tid & 63;
  const int quad = lane >> 4, l16 = lane & 15;
  const int wm = (wave >> 1) * 64, wn = (wave & 1) * 64;
  const int m0 = blockIdx.x * 128, n0 = blockIdx.y * 128;

  f32x4 acc[4][4] = {};

  for (int k0 = 0; k0 < K; k0 += 32) {
    __syncthreads();
#pragma unroll
    for (int it = 0; it < 2; ++it) {
      int e = tid * 8 + it * 2048;
      int r = e >> 5, c = e & 31;
      gload_lds16(A + (size_t)(m0 + r) * K + k0 + c,
                  (const char*)As + it * 4096 + wave * 1024);
    }
#pragma unroll
    for (int it = 0; it < 2; ++it) {
      int e = tid * 8 + it * 2048;
      int r = e >> 5, c = e & 31;
      gload_lds16(BT + (size_t)(n0 + r) * K + k0 + c,
                  (const char*)Bs + it * 4096 + wave * 1024);
    }
    __syncthreads();
    bf16x8 af[4], bfg[4];
#pragma unroll
    for (int t = 0; t < 4; ++t)
      af[t] = *(const bf16x8*)(As + (wm + t * 16 + l16) * 32 + quad * 8);
#pragma unroll
    for (int t = 0; t < 4; ++t)
      bfg[t] = *(const bf16x8*)(Bs + (wn + t * 16 + l16) * 32 + quad * 8);
#pragma unroll
    for (int tm = 0; tm < 4; ++tm)
#pragma unroll
      for (int tn = 0; tn < 4; ++tn)
        acc[tm][tn] = __builtin_amdgcn_mfma_f32_16x16x32_bf16(
            af[tm], bfg[tn], acc[tm][tn], 0, 0, 0);
  }

#pragma unroll
  for (int tn = 0; tn < 4; ++tn) {
    int n = n0 + wn + tn * 16 + l16;
    float bv = bias[n];
#pragma unroll
    for (int tm = 0; tm < 4; ++tm) {
      int mb = m0 + wm + tm * 16 + quad * 4;
#pragma unroll
      for (int r = 0; r < 4; ++r) {
        float v = acc[tm][tn][r] + bv;
        if (BF16OUT)
          ((short*)Cv)[(size_t)(mb + r) * N + n] = f2bf(v);
        else
          ((float*)Cv)[(size_t)(mb + r) * N + n] = v;
      }
    }
  }
}

// ---------------------------------------------------------------------------
// Kernel 5: causal flash attention, one head-batch (bh) per blockIdx.y,
// q-tile pair {p, 15-p} per blockIdx.x. 128-row Q tile, 128-col K tiles.
// Q,K read from qkv buffer (bf16), V^T from vT, O -> obuf (b,s,h*128+d) bf16.
// ---------------------------------------------------------------------------
__global__ __launch_bounds__(256, 2) void attn_kernel(
    const short* __restrict__ qkv, const short* __restrict__ vT,
    short* __restrict__ obuf) {
  __shared__ __align__(16) short KPs[128 * 128];  // K tile, then reused for P
  __shared__ __align__(16) short Vs[128 * 128];   // V^T tile: [d][s]
  const int tid = threadIdx.x;
  const int wave = tid >> 6, lane = tid & 63;
  const int quad = lane >> 4, l16 = lane & 15;
  const int bh = blockIdx.y, b = bh >> 4, h = bh & 15;
  const int pair = blockIdx.x;

  const short* qbase = qkv + (size_t)b * 2048 * 6144 + h * 128;
  const short* kbase = qkv + (size_t)b * 2048 * 6144 + 2048 + h * 128;
  const short* vtbase = vT + (size_t)bh * 128 * 2048;
  short* obase = obuf + (size_t)b * 2048 * 2048 + h * 128;

  for (int half = 0; half < 2; ++half) {
    const int qt = half ? (15 - pair) : pair;
    const int q0 = qt * 128;

    // Q fragments resident in registers: 2 m-tiles x 4 k-steps
    bf16x8 qf[2][4];
#pragma unroll
    for (int tm = 0; tm < 2; ++tm)
#pragma unroll
      for (int kk = 0; kk < 4; ++kk)
        qf[tm][kk] = *(const bf16x8*)(
            qbase + (size_t)(q0 + wave * 32 + tm * 16 + l16) * 6144 +
            kk * 32 + quad * 8);

    f32x4 acco[2][8] = {};
    float mrun[2][4], lrun[2][4];
#pragma unroll
    for (int tm = 0; tm < 2; ++tm)
#pragma unroll
      for (int r = 0; r < 4; ++r) { mrun[tm][r] = -1e30f; lrun[tm][r] = 0.f; }

    for (int kt = 0; kt <= qt; ++kt) {
      const int k0 = kt * 128;
      __syncthreads();  // prior iter's P/V reads done before restage
#pragma unroll
      for (int it = 0; it < 8; ++it) {
        int e = tid * 8 + it * 2048;
        int r = e >> 7, c = e & 127;
        gload_lds16(kbase + (size_t)(k0 + r) * 6144 + c,
                    (const char*)KPs + it * 4096 + wave * 1024);
      }
#pragma unroll
      for (int it = 0; it < 8; ++it) {
        int e = tid * 8 + it * 2048;
        int r = e >> 7, c = e & 127;
        gload_lds16(vtbase + (size_t)r * 2048 + k0 + c,
                    (const char*)Vs + it * 4096 + wave * 1024);
      }
      __syncthreads();

      // ---- S = Q K^T (wave computes its own 32 rows x 128 cols) ----
      f32x4 accs[2][8] = {};
#pragma unroll
      for (int kk = 0; kk < 4; ++kk) {
        bf16x8 bfg[8];
#pragma unroll
        for (int tn = 0; tn < 8; ++tn)
          bfg[tn] = *(const bf16x8*)(KPs + (tn * 16 + l16) * 128 + kk * 32 + quad * 8);
#pragma unroll
        for (int tm = 0; tm < 2; ++tm)
#pragma unroll
          for (int tn = 0; tn < 8; ++tn)
            accs[tm][tn] = __builtin_amdgcn_mfma_f32_16x16x32_bf16(
                qf[tm][kk], bfg[tn], accs[tm][tn], 0, 0, 0);
      }

      // ---- scale + causal mask (diagonal tile only) ----
      const bool diag = (kt == qt);
#pragma unroll
      for (int tm = 0; tm < 2; ++tm)
#pragma unroll
        for (int tn = 0; tn < 8; ++tn)
#pragma unroll
          for (int r = 0; r < 4; ++r) {
            float s = accs[tm][tn][r] * SOFT_SCALE;
            if (diag) {
              int rowl = wave * 32 + tm * 16 + quad * 4 + r;
              int coll = tn * 16 + l16;
              if (coll > rowl) s = -1e30f;
            }
            accs[tm][tn][r] = s;
          }

      // ---- online softmax (rows wave-local; reduce over 16-lane quad grp) --
#pragma unroll
      for (int tm = 0; tm < 2; ++tm)
#pragma unroll
        for (int r = 0; r < 4; ++r) {
          float mx = accs[tm][0][r];
#pragma unroll
          for (int tn = 1; tn < 8; ++tn) mx = fmaxf(mx, accs[tm][tn][r]);
#pragma unroll
          for (int off = 1; off < 16; off <<= 1)
            mx = fmaxf(mx, __shfl_xor(mx, off, 64));
          float mn = fmaxf(mrun[tm][r], mx);
          float al = exp2f(mrun[tm][r] - mn);
          mrun[tm][r] = mn;
          float rs = 0.f;
#pragma unroll
          for (int tn = 0; tn < 8; ++tn) {
            float p = exp2f(accs[tm][tn][r] - mn);
            accs[tm][tn][r] = p;
            rs += p;
          }
#pragma unroll
          for (int off = 1; off < 16; off <<= 1)
            rs += __shfl_xor(rs, off, 64);
          lrun[tm][r] = lrun[tm][r] * al + rs;
#pragma unroll
          for (int tn = 0; tn < 8; ++tn) acco[tm][tn][r] *= al;
        }

      __syncthreads();  // all waves done reading K tile before P overwrites it

      // ---- write P~ (bf16) into KPs (C-layout -> plain [row][col]) ----
#pragma unroll
      for (int tm = 0; tm < 2; ++tm)
#pragma unroll
        for (int r = 0; r < 4; ++r) {
          int row = wave * 32 + tm * 16 + quad * 4 + r;
#pragma unroll
          for (int tn = 0; tn < 8; ++tn)
            KPs[row * 128 + tn * 16 + l16] = f2bf(accs[tm][tn][r]);
        }

      // ---- O += P~ V  (wave reads only its own P rows: no barrier needed) --
#pragma unroll
      for (int kk = 0; kk < 4; ++kk) {
        bf16x8 bfg[8];
#pragma unroll
        for (int tn = 0; tn < 8; ++tn)
          bfg[tn] = *(const bf16x8*)(Vs + (tn * 16 + l16) * 128 + kk * 32 + quad * 8);
#pragma unroll
        for (int tm = 0; tm < 2; ++tm) {
          bf16x8 av = *(const bf16x8*)(
              KPs + (wave * 32 + tm * 16 + l16) * 128 + kk * 32 + quad * 8);
#pragma unroll
          for (int tn = 0; tn < 8; ++tn)
            acco[tm][tn] = __builtin_amdgcn_mfma_f32_16x16x32_bf16(
                av, bfg[tn], acco[tm][tn], 0, 0, 0);
        }
      }
    }

    // ---- epilogue: O /= l, store bf16 to (b, s, h*128+d) ----
#pragma unroll
    for (int tm = 0; tm < 2; ++tm) {
      float inv[4];
#pragma unroll
      for (int r = 0; r < 4; ++r) inv[r] = 1.f / lrun[tm][r];
#pragma unroll
      for (int r = 0; r < 4; ++r) {
        int row = q0 + wave * 32 + tm * 16 + quad * 4 + r;
#pragma unroll
        for (int tn = 0; tn < 8; ++tn)
          obase[(size_t)row * 2048 + tn * 16 + l16] =
              f2bf(acco[tm][tn][r] * inv[r]);
      }
    }
  }
}

// ---------------------------------------------------------------------------
extern "C" void kernel_launch(void* const* d_in, const int* in_sizes, int n_in,
                              void* d_out, int out_size, void* d_ws,
                              size_t ws_size, hipStream_t stream) {
  (void)in_sizes; (void)n_in; (void)out_size; (void)ws_size;
  const float* x    = (const float*)d_in[0];
  const float* Wqkv = (const float*)d_in[1];
  const float* bqkv = (const float*)d_in[2];
  const float* Wout = (const float*)d_in[3];
  const float* bout = (const float*)d_in[4];
  float* out = (float*)d_out;

  char* ws = (char*)d_ws;
  short* xb    = (short*)(ws);                    // 16,777,216 B
  short* wqkvT = (short*)(ws + 16777216);         // 25,165,824 B
  short* woutT = (short*)(ws + 41943040);         //  8,388,608 B
  short* qkv   = (short*)(ws + 50331648);         // 50,331,648 B
  short* vTb   = (short*)(ws + 100663296);        // 16,777,216 B
  short* obuf  = (short*)(ws + 117440512);        // 16,777,216 B -> 128 MiB total

  // 1) casts / transposes
  cast_f32_bf16<<<4096, 256, 0, stream>>>(x, xb, 1048576);
  transpose_cast_w<<<dim3(64, 192), 256, 0, stream>>>(Wqkv, wqkvT, 2048, 6144);
  transpose_cast_w<<<dim3(64, 64), 256, 0, stream>>>(Wout, woutT, 2048, 2048);

  // 2) qkv = x @ W_qkv + b_qkv   (M=4096, N=6144, K=2048) -> bf16
  gemm_bt<1><<<dim3(32, 48), 256, 0, stream>>>(xb, wqkvT, (void*)qkv, bqkv,
                                               4096, 6144, 2048);

  // 3) per-head V^T
  transpose_v<<<dim3(32, 2, 32), 256, 0, stream>>>(qkv, vTb);

  // 4) attention
  attn_kernel<<<dim3(8, 32), 256, 0, stream>>>(qkv, vTb, obuf);

  // 5) y = O @ W_out + b_out     (M=4096, N=2048, K=2048) -> fp32
  gemm_bt<0><<<dim3(32, 16), 256, 0, stream>>>(obuf, woutT, (void*)out, bout,
                                               4096, 2048, 2048);
}

// Round 2
// 434.200 us; speedup vs baseline: 1.1856x; 1.1856x over previous
//
#include <hip/hip_runtime.h>
#include <stdint.h>
#include <stddef.h>

// ---------------------------------------------------------------------------
// TinySelfAttention on MI355X (gfx950), bf16 MFMA pipeline:
//   1) cast x -> bf16
//   2) transpose+cast W_qkv, W_out -> bf16 B^T form
//   3) GEMM (m97 structure): qkv = x @ W_qkv + b_qkv   (bf16 out)
//   4) transpose V slice of qkv -> per-head V^T (bf16)
//   5) flash attention (causal, online softmax), O in (b,s,h*hd) bf16
//      - K/V staged in MFMA-fragment-linear LDS layout (conflict-free reads)
//      - 64-row Q tiles, pair {p, 31-p} per block -> 512 uniform blocks,
//        2 blocks/CU
//   6) GEMM: y = O @ W_out + b_out  (fp32 out)
// ---------------------------------------------------------------------------

typedef __attribute__((ext_vector_type(8))) short bf16x8;   // 8 x bf16 = 4 VGPRs
typedef __attribute__((ext_vector_type(4))) float f32x4;    // MFMA accumulator

#define SOFT_SCALE 0.12751743075419806f  // (1/sqrt(128)) * log2(e)

__device__ __forceinline__ short f2bf(float f) {
  union { float f; unsigned u; } v; v.f = f;
  unsigned u = v.u + 0x7fffu + ((v.u >> 16) & 1u);  // RNE
  return (short)(u >> 16);
}

__device__ __forceinline__ void gload_lds16(const void* g, const void* l) {
  // async global->LDS, 16B per lane; LDS dest = wave-uniform base + lane*16
  __builtin_amdgcn_global_load_lds(
      (__attribute__((address_space(1))) void*)(uintptr_t)g,
      (__attribute__((address_space(3))) void*)(uintptr_t)l,
      16, 0, 0);
}

// ---------------------------------------------------------------------------
// Kernel 1: fp32 -> bf16 cast, 8 elems/thread
// ---------------------------------------------------------------------------
__global__ __launch_bounds__(256) void cast_f32_bf16(
    const float* __restrict__ in, short* __restrict__ out, int n8) {
  int i = blockIdx.x * 256 + threadIdx.x;
  if (i >= n8) return;
  float4 a = ((const float4*)in)[i * 2];
  float4 b = ((const float4*)in)[i * 2 + 1];
  bf16x8 o;
  o[0] = f2bf(a.x); o[1] = f2bf(a.y); o[2] = f2bf(a.z); o[3] = f2bf(a.w);
  o[4] = f2bf(b.x); o[5] = f2bf(b.y); o[6] = f2bf(b.z); o[7] = f2bf(b.w);
  ((bf16x8*)out)[i] = o;
}

// ---------------------------------------------------------------------------
// Kernel 2: W [K][N] fp32 -> WT [N][K] bf16, 32x32 tiles
// ---------------------------------------------------------------------------
__global__ __launch_bounds__(256) void transpose_cast_w(
    const float* __restrict__ W, short* __restrict__ WT, int K, int N) {
  __shared__ short t[32][33];
  int k0 = blockIdx.x * 32, n0 = blockIdx.y * 32;
  int r = threadIdx.x >> 3;
  int c = (threadIdx.x & 7) * 4;
  float4 v = *(const float4*)(W + (size_t)(k0 + r) * N + n0 + c);
  t[r][c + 0] = f2bf(v.x); t[r][c + 1] = f2bf(v.y);
  t[r][c + 2] = f2bf(v.z); t[r][c + 3] = f2bf(v.w);
  __syncthreads();
  short4 o;
  o.x = t[c + 0][r]; o.y = t[c + 1][r]; o.z = t[c + 2][r]; o.w = t[c + 3][r];
  *(short4*)(WT + (size_t)(n0 + r) * K + k0 + c) = o;
}

// ---------------------------------------------------------------------------
// Kernel 3: V slice of qkv (b,s, 4096 + h*128 + d) -> vT[bh][d][s], 64x64 tiles
// grid: (s-tiles=32, d-tiles=2, bh=32)
// ---------------------------------------------------------------------------
__global__ __launch_bounds__(256) void transpose_v(
    const short* __restrict__ qkv, short* __restrict__ vT) {
  __shared__ short t[64][72];
  int bh = blockIdx.z, b = bh >> 4, h = bh & 15;
  int s0 = blockIdx.x * 64, d0 = blockIdx.y * 64;
  const short* src = qkv + (size_t)b * 2048 * 6144 + 4096 + h * 128 + d0;
  short* dst = vT + (size_t)bh * 128 * 2048;
#pragma unroll
  for (int it = 0; it < 2; ++it) {
    int e = threadIdx.x * 8 + it * 2048;
    int sr = e >> 6, sc = e & 63;
    bf16x8 v = *(const bf16x8*)(src + (size_t)(s0 + sr) * 6144 + sc);
#pragma unroll
    for (int j = 0; j < 8; ++j) t[sr][sc + j] = v[j];
  }
  __syncthreads();
#pragma unroll
  for (int it = 0; it < 2; ++it) {
    int e = threadIdx.x * 8 + it * 2048;
    int dr = e >> 6, dc = e & 63;
    bf16x8 o;
#pragma unroll
    for (int j = 0; j < 8; ++j) o[j] = t[dc + j][dr];
    *(bf16x8*)(dst + (size_t)(d0 + dr) * 2048 + s0 + dc) = o;
  }
}

// ---------------------------------------------------------------------------
// Kernel 4: GEMM  C[M][N] = A[M][K] @ BT[N][K]^T + bias  (m97 structure)
// 128x128 tile, BK=32, 4 waves, 4x4 16x16x32 MFMAs per wave.
// BF16OUT=1 -> C is bf16 (short*), else fp32 (float*)
// ---------------------------------------------------------------------------
template <int BF16OUT>
__global__ __launch_bounds__(256) void gemm_bt(
    const short* __restrict__ A, const short* __restrict__ BT,
    void* __restrict__ Cv, const float* __restrict__ bias,
    int M, int N, int K) {
  __shared__ __align__(16) short As[128 * 32];
  __shared__ __align__(16) short Bs[128 * 32];
  const int tid = threadIdx.x;
  const int wave = tid >> 6, lane = tid & 63;
  const int quad = lane >> 4, l16 = lane & 15;
  const int wm = (wave >> 1) * 64, wn = (wave & 1) * 64;
  const int m0 = blockIdx.x * 128, n0 = blockIdx.y * 128;

  f32x4 acc[4][4] = {};

  for (int k0 = 0; k0 < K; k0 += 32) {
    __syncthreads();
#pragma unroll
    for (int it = 0; it < 2; ++it) {
      int e = tid * 8 + it * 2048;
      int r = e >> 5, c = e & 31;
      gload_lds16(A + (size_t)(m0 + r) * K + k0 + c,
                  (const char*)As + it * 4096 + wave * 1024);
    }
#pragma unroll
    for (int it = 0; it < 2; ++it) {
      int e = tid * 8 + it * 2048;
      int r = e >> 5, c = e & 31;
      gload_lds16(BT + (size_t)(n0 + r) * K + k0 + c,
                  (const char*)Bs + it * 4096 + wave * 1024);
    }
    __syncthreads();
    bf16x8 af[4], bfg[4];
#pragma unroll
    for (int t = 0; t < 4; ++t)
      af[t] = *(const bf16x8*)(As + (wm + t * 16 + l16) * 32 + quad * 8);
#pragma unroll
    for (int t = 0; t < 4; ++t)
      bfg[t] = *(const bf16x8*)(Bs + (wn + t * 16 + l16) * 32 + quad * 8);
#pragma unroll
    for (int tm = 0; tm < 4; ++tm)
#pragma unroll
      for (int tn = 0; tn < 4; ++tn)
        acc[tm][tn] = __builtin_amdgcn_mfma_f32_16x16x32_bf16(
            af[tm], bfg[tn], acc[tm][tn], 0, 0, 0);
  }

#pragma unroll
  for (int tn = 0; tn < 4; ++tn) {
    int n = n0 + wn + tn * 16 + l16;
    float bv = bias[n];
#pragma unroll
    for (int tm = 0; tm < 4; ++tm) {
      int mb = m0 + wm + tm * 16 + quad * 4;
#pragma unroll
      for (int r = 0; r < 4; ++r) {
        float v = acc[tm][tn][r] + bv;
        if (BF16OUT)
          ((short*)Cv)[(size_t)(mb + r) * N + n] = f2bf(v);
        else
          ((float*)Cv)[(size_t)(mb + r) * N + n] = v;
      }
    }
  }
}

// ---------------------------------------------------------------------------
// Kernel 5: causal flash attention v2.
// grid (16, 32): blockIdx.x = pair p in {pp, 31-pp} of 64-row Q tiles,
// blockIdx.y = bh. 128-col K tiles. K/V staged fragment-linear in LDS
// (conflict-free b128 reads); P in padded LDS overlaying K region.
// 512 uniform blocks (17 kt-iters each), 2 blocks/CU.
// ---------------------------------------------------------------------------
__global__ __launch_bounds__(256, 2) void attn_kernel(
    const short* __restrict__ qkv, const short* __restrict__ vT,
    short* __restrict__ obuf) {
  // Ks: 32 chunks (kk,tn) of 1024B fragment-linear K tile; overlaid by
  // PL[64][136] (padded) after QK^T. Vs: same chunk layout for V^T tile.
  __shared__ __align__(16) short Ks[16384];
  __shared__ __align__(16) short Vs[16384];
  const int tid = threadIdx.x;
  const int wave = tid >> 6, lane = tid & 63;
  const int quad = lane >> 4, l16 = lane & 15;
  const int bh = blockIdx.y, b = bh >> 4, h = bh & 15;
  const int pp = blockIdx.x;

  const short* qbase = qkv + (size_t)b * 2048 * 6144 + h * 128;
  const short* kbase = qkv + (size_t)b * 2048 * 6144 + 2048 + h * 128;
  const short* vtbase = vT + (size_t)bh * 128 * 2048;
  short* obase = obuf + (size_t)b * 2048 * 2048 + h * 128;

  // staging source sub-indices (fragment-linear permutation)
  const int srow = lane >> 2;        // row within 16-row chunk group
  const int scol = (lane & 3) * 8;   // col offset within 32-col k-chunk

  for (int half = 0; half < 2; ++half) {
    const int p = half ? (31 - pp) : pp;
    const int q0 = p * 64;
    const int nkt = (p >> 1) + 1;  // # of 128-col K tiles (causal)

    // Q fragments resident in registers: wave owns 16 q-rows, 4 k-steps
    bf16x8 qf[4];
#pragma unroll
    for (int kk = 0; kk < 4; ++kk)
      qf[kk] = *(const bf16x8*)(
          qbase + (size_t)(q0 + wave * 16 + l16) * 6144 + kk * 32 + quad * 8);

    f32x4 acco[8] = {};
    float mrun[4], lrun[4];
#pragma unroll
    for (int r = 0; r < 4; ++r) { mrun[r] = -1e30f; lrun[r] = 0.f; }

    for (int kt = 0; kt < nkt; ++kt) {
      const int k0 = kt * 128;
      __syncthreads();  // prior iter's PL/Vs reads done before restage
      // ---- stage K tile fragment-linear: chunk (kk=wave, tn=it) ----
#pragma unroll
      for (int it = 0; it < 8; ++it) {
        gload_lds16(
            kbase + (size_t)(k0 + it * 16 + srow) * 6144 + wave * 32 + scol,
            (const char*)Ks + (wave * 8 + it) * 1024);
      }
      // ---- stage V^T tile fragment-linear ----
#pragma unroll
      for (int it = 0; it < 8; ++it) {
        gload_lds16(
            vtbase + (size_t)(it * 16 + srow) * 2048 + k0 + wave * 32 + scol,
            (const char*)Vs + (wave * 8 + it) * 1024);
      }
      __syncthreads();

      // ---- S = Q K^T (wave: its 16 q-rows x 128 keys) ----
      f32x4 accs[8] = {};
#pragma unroll
      for (int kk = 0; kk < 4; ++kk) {
        bf16x8 bfg[8];
#pragma unroll
        for (int tn = 0; tn < 8; ++tn)
          bfg[tn] = *(const bf16x8*)((const char*)Ks + (kk * 8 + tn) * 1024 +
                                     l16 * 64 + quad * 16);
#pragma unroll
        for (int tn = 0; tn < 8; ++tn)
          accs[tn] = __builtin_amdgcn_mfma_f32_16x16x32_bf16(
              qf[kk], bfg[tn], accs[tn], 0, 0, 0);
      }

      // ---- scale + causal mask (last tile only, global indices) ----
      const bool diag = (kt == nkt - 1);
#pragma unroll
      for (int tn = 0; tn < 8; ++tn)
#pragma unroll
        for (int r = 0; r < 4; ++r) {
          float s = accs[tn][r] * SOFT_SCALE;
          if (diag) {
            int grow = q0 + wave * 16 + quad * 4 + r;
            int gcol = k0 + tn * 16 + l16;
            if (gcol > grow) s = -1e30f;
          }
          accs[tn][r] = s;
        }

      // ---- online softmax (rows wave-local; reduce over 16 l16 lanes) ----
#pragma unroll
      for (int r = 0; r < 4; ++r) {
        float mx = accs[0][r];
#pragma unroll
        for (int tn = 1; tn < 8; ++tn) mx = fmaxf(mx, accs[tn][r]);
#pragma unroll
        for (int off = 1; off < 16; off <<= 1)
          mx = fmaxf(mx, __shfl_xor(mx, off, 64));
        float mn = fmaxf(mrun[r], mx);
        float al = exp2f(mrun[r] - mn);
        mrun[r] = mn;
        float rs = 0.f;
#pragma unroll
        for (int tn = 0; tn < 8; ++tn) {
          float pv = exp2f(accs[tn][r] - mn);
          accs[tn][r] = pv;
          rs += pv;
        }
#pragma unroll
        for (int off = 1; off < 16; off <<= 1)
          rs += __shfl_xor(rs, off, 64);
        lrun[r] = lrun[r] * al + rs;
#pragma unroll
        for (int tn = 0; tn < 8; ++tn) acco[tn][r] *= al;
      }

      __syncthreads();  // all waves done reading Ks before PL overwrites it

      // ---- write P~ (bf16) into PL[64][136] (padded, overlays Ks) ----
#pragma unroll
      for (int r = 0; r < 4; ++r) {
        int row = wave * 16 + quad * 4 + r;
#pragma unroll
        for (int tn = 0; tn < 8; ++tn)
          Ks[row * 136 + tn * 16 + l16] = f2bf(accs[tn][r]);
      }

      // ---- O += P~ V (wave reads only its own 16 P rows) ----
#pragma unroll
      for (int kk = 0; kk < 4; ++kk) {
        bf16x8 av = *(const bf16x8*)(Ks + (wave * 16 + l16) * 136 + kk * 32 +
                                     quad * 8);
        bf16x8 bfg[8];
#pragma unroll
        for (int tn = 0; tn < 8; ++tn)
          bfg[tn] = *(const bf16x8*)((const char*)Vs + (kk * 8 + tn) * 1024 +
                                     l16 * 64 + quad * 16);
#pragma unroll
        for (int tn = 0; tn < 8; ++tn)
          acco[tn] = __builtin_amdgcn_mfma_f32_16x16x32_bf16(
              av, bfg[tn], acco[tn], 0, 0, 0);
      }
    }

    // ---- epilogue: O /= l, store bf16 to (b, s, h*128+d) ----
    float inv[4];
#pragma unroll
    for (int r = 0; r < 4; ++r) inv[r] = 1.f / lrun[r];
#pragma unroll
    for (int r = 0; r < 4; ++r) {
      int row = q0 + wave * 16 + quad * 4 + r;
#pragma unroll
      for (int tn = 0; tn < 8; ++tn)
        obase[(size_t)row * 2048 + tn * 16 + l16] = f2bf(acco[tn][r] * inv[r]);
    }
  }
}

// ---------------------------------------------------------------------------
extern "C" void kernel_launch(void* const* d_in, const int* in_sizes, int n_in,
                              void* d_out, int out_size, void* d_ws,
                              size_t ws_size, hipStream_t stream) {
  (void)in_sizes; (void)n_in; (void)out_size; (void)ws_size;
  const float* x    = (const float*)d_in[0];
  const float* Wqkv = (const float*)d_in[1];
  const float* bqkv = (const float*)d_in[2];
  const float* Wout = (const float*)d_in[3];
  const float* bout = (const float*)d_in[4];
  float* out = (float*)d_out;

  char* ws = (char*)d_ws;
  short* xb    = (short*)(ws);                    // 16,777,216 B
  short* wqkvT = (short*)(ws + 16777216);         // 25,165,824 B
  short* woutT = (short*)(ws + 41943040);         //  8,388,608 B
  short* qkv   = (short*)(ws + 50331648);         // 50,331,648 B
  short* vTb   = (short*)(ws + 100663296);        // 16,777,216 B
  short* obuf  = (short*)(ws + 117440512);        // 16,777,216 B -> 128 MiB total

  // 1) casts / transposes
  cast_f32_bf16<<<4096, 256, 0, stream>>>(x, xb, 1048576);
  transpose_cast_w<<<dim3(64, 192), 256, 0, stream>>>(Wqkv, wqkvT, 2048, 6144);
  transpose_cast_w<<<dim3(64, 64), 256, 0, stream>>>(Wout, woutT, 2048, 2048);

  // 2) qkv = x @ W_qkv + b_qkv   (M=4096, N=6144, K=2048) -> bf16
  gemm_bt<1><<<dim3(32, 48), 256, 0, stream>>>(xb, wqkvT, (void*)qkv, bqkv,
                                               4096, 6144, 2048);

  // 3) per-head V^T
  transpose_v<<<dim3(32, 2, 32), 256, 0, stream>>>(qkv, vTb);

  // 4) attention: 512 uniform blocks, 2/CU
  attn_kernel<<<dim3(16, 32), 256, 0, stream>>>(qkv, vTb, obuf);

  // 5) y = O @ W_out + b_out     (M=4096, N=2048, K=2048) -> fp32
  gemm_bt<0><<<dim3(32, 16), 256, 0, stream>>>(obuf, woutT, (void*)out, bout,
                                               4096, 2048, 2048);
}